// Round 7
// baseline (683.145 us; speedup 1.0000x reference)
//
#include <hip/hip_runtime.h>
#include <cstdio>
#include <math.h>

typedef unsigned short u16;
typedef float f32x4 __attribute__((ext_vector_type(4)));
typedef __bf16 bf16x8 __attribute__((ext_vector_type(8)));
typedef u16 u16x4 __attribute__((ext_vector_type(4)));
typedef u16 u16x8 __attribute__((ext_vector_type(8)));

__device__ __forceinline__ u16 f2bf(float x) {
  unsigned u = __float_as_uint(x);
  u = (u + 0x7FFFu + ((u >> 16) & 1u)) >> 16;
  return (u16)u;
}
__device__ __forceinline__ float bf2f(u16 x) {
  return __uint_as_float(((unsigned)x) << 16);
}

__device__ __forceinline__ f32x4 mfma_bf16(bf16x8 a, bf16x8 b, f32x4 c) {
  return __builtin_amdgcn_mfma_f32_16x16x32_bf16(a, b, c, 0, 0, 0);
}

// async global->LDS, 16B per lane. LDS dest = wave-uniform base + lane*16.
__device__ __forceinline__ void gload_lds16(const void* g, void* l) {
  __builtin_amdgcn_global_load_lds(
      (const __attribute__((address_space(1))) void*)g,
      (__attribute__((address_space(3))) void*)l, 16, 0, 0);
}

// C[m,n] = scale * sum_k A[m,k] * B[n,k]   (both operands K-contiguous)
// BM=256 x BN=256, BK=32. 512 threads = 8 waves (2M x 4N), per-wave 128x64 out.
// QUAD-buffered LDS (32KB/buf, 128KB total): tile t reads buf[t&3]; tile t+3
// staged into buf[(t+3)&3] during t (last reader was t-1, already past its
// lgkm-waited barrier -> race-free; issue-to-use ~3 tiles > HBM latency).
// Counted vmcnt(8) at tile boundary keeps t+2/t+3's 8 loads in flight (T4).
// Rows are 64B (4 x 16B slots): XOR-swizzle slot ^= (row>>1)&3 spreads each
// ds_read_b128 as 2 lanes per 4-bank group (free); applied via pre-swizzled
// global SOURCE (linear gload dest) + swizzled read address (T2).
// Per tile: P0 {read A m0-3 + B n0-3; stage A(t+3); bar; 16 MFMA; bar}
//           P1 {read A m4-7 (B reused); stage B(t+3); bar; 16 MFMA; vmcnt; bar}
// Requires nt >= 3 (K >= 96), M%256==0, N%256==0, K%32==0.
// Block-index modes (causal work must be XCD-BALANCED, r5 lesson):
//  XSWZ: T1 XCD swizzle for uniform grids (gx pow2, nwg%8==0).
//  TRI:  compact causal grid: gridDim.x == 36 == live tiles of 8x8 256x256
//        triangular tiling (bx <= by); equal-work tiles -> round-robin balances.
//  SWAPXY: bx=blockIdx.y, by=blockIdx.x (PV: variable-work t-dim on y).
template <bool BF16OUT, bool XSWZ, bool TRI, bool KLIMIT, bool SWAPXY>
__global__ __launch_bounds__(512, 2) void gemm_bt(
    const u16* __restrict__ A, const u16* __restrict__ B, void* __restrict__ Cv,
    int K, int lda, int ldb, int ldc,
    long long sAz, long long sBz, long long sCz, float scale)
{
  int bx, by;
  if (TRI) {
    const int j = blockIdx.x;
    int r = (int)((sqrtf(8.f * j + 1.f) - 1.f) * 0.5f);
    while (r * (r + 1) / 2 > j) --r;
    while ((r + 1) * (r + 2) / 2 <= j) ++r;
    by = r;
    bx = j - r * (r + 1) / 2;
  } else if (SWAPXY) {
    bx = blockIdx.y; by = blockIdx.x;
  } else if (XSWZ) {
    const int gx = gridDim.x;
    const int nwg = gx * gridDim.y;
    const int f0 = blockIdx.x + gx * blockIdx.y;
    const int f = (f0 & 7) * (nwg >> 3) + (f0 >> 3);
    bx = f & (gx - 1);
    by = f / gx;
  } else {
    bx = blockIdx.x; by = blockIdx.y;
  }

  const int n0 = bx * 256;
  const int m0 = by * 256;
  const int z = blockIdx.z;
  A += (long long)z * sAz;
  B += (long long)z * sBz;

  const int tid = threadIdx.x;
  const int wave = tid >> 6, lane = tid & 63;
  const int wr = wave >> 2, wc = wave & 3;  // 2M x 4N wave grid

  // per buffer: A [256][32] u16 at 0..8191, B [256][32] u16 at 8192..16383
  __shared__ u16 lds[4][16384];

  f32x4 acc[8][4] = {};

  int kEnd = K;
  if (KLIMIT) { int ke = n0 + 256; kEnd = ke < K ? ke : K; }  // P[t,s]==0 for s>t
  const int nt = kEnd >> 5;  // >= 8 for all our launches

  // ---- staging: one gload call = 512 lanes x 16B = 128 rows of 64B.
  // lane l (in wave w, call c): row = c*128 + w*16 + (l>>2), phys slot = l&3.
  // logical slot = phys ^ ((row>>1)&3) = (l&3) ^ ((l>>3)&3)  [c*64, w*8 = 0 mod 4]
  const int sOff = ((lane & 3) ^ ((lane >> 3) & 3)) * 8;  // element offset in row
  const u16* gAs = A + (long long)(m0 + wave * 16 + (lane >> 2)) * lda + sOff;
  const u16* gBs = B + (long long)(n0 + wave * 16 + (lane >> 2)) * ldb + sOff;

  // ---- read: logical slot g lives at phys slot g ^ ((row>>1)&3); for rows
  // (base + m*16 + frow) with base,m*16 = 0 mod 8: (row>>1)&3 == (frow>>1)&3.
  const int frow = lane & 15, g = lane >> 4;
  const int ps = g ^ ((frow >> 1) & 3);
  const int aBase = (wr * 128 + frow) * 32 + ps * 8;          // + m*512
  const int bBase = 8192 + (wc * 64 + frow) * 32 + ps * 8;    // + n*512

#define STAGE_A(T, BUF)                                                        \
  {                                                                            \
    const long long kc = (long long)(T) * 32;                                  \
    _Pragma("unroll")                                                          \
    for (int c = 0; c < 2; ++c)                                                \
      gload_lds16(gAs + (long long)(c * 128) * lda + kc,                       \
                  &lds[BUF][c * 4096 + wave * 512]);                           \
  }
#define STAGE_B(T, BUF)                                                        \
  {                                                                            \
    const long long kc = (long long)(T) * 32;                                  \
    _Pragma("unroll")                                                          \
    for (int c = 0; c < 2; ++c)                                                \
      gload_lds16(gBs + (long long)(c * 128) * ldb + kc,                       \
                  &lds[BUF][8192 + c * 4096 + wave * 512]);                    \
  }

  // ---- prologue: stage t0..t2 -> buf0..2; retire t0's 4 (12 -> 8 in flight)
  STAGE_A(0, 0) STAGE_B(0, 0)
  STAGE_A(1, 1) STAGE_B(1, 1)
  STAGE_A(2, 2) STAGE_B(2, 2)
  asm volatile("s_waitcnt vmcnt(8)" ::: "memory");
  __builtin_amdgcn_s_barrier();

  int cur = 0, nxt = 3;
  for (int t = 0; t < nt; ++t) {
    const u16* bb = &lds[cur][0];
    const int rem = nt - 1 - t;
    bf16x8 af[4], bf[4];

    // ---- phase 1: read A m0-3 + B n0-3; stage A(t+3); MFMA acc[0..3][*]
#pragma unroll
    for (int m = 0; m < 4; ++m) af[m] = *(const bf16x8*)(bb + aBase + m * 512);
#pragma unroll
    for (int n = 0; n < 4; ++n) bf[n] = *(const bf16x8*)(bb + bBase + n * 512);
    if (rem >= 3) STAGE_A(t + 3, nxt)
    __builtin_amdgcn_s_barrier();
    __builtin_amdgcn_s_setprio(1);
#pragma unroll
    for (int m = 0; m < 4; ++m)
#pragma unroll
      for (int n = 0; n < 4; ++n)
        acc[m][n] = mfma_bf16(af[m], bf[n], acc[m][n]);
    __builtin_amdgcn_s_setprio(0);
    __builtin_amdgcn_s_barrier();

    // ---- phase 2: read A m4-7 (B reused in regs); stage B(t+3); MFMA acc[4..7][*]
#pragma unroll
    for (int m = 0; m < 4; ++m) af[m] = *(const bf16x8*)(bb + aBase + (4 + m) * 512);
    if (rem >= 3) STAGE_B(t + 3, nxt)
    __builtin_amdgcn_s_barrier();
    __builtin_amdgcn_s_setprio(1);
#pragma unroll
    for (int m = 0; m < 4; ++m)
#pragma unroll
      for (int n = 0; n < 4; ++n)
        acc[4 + m][n] = mfma_bf16(af[m], bf[n], acc[4 + m][n]);
    __builtin_amdgcn_s_setprio(0);
    // ---- boundary: retire t+1's loads; keep later tiles' loads in flight
    if (rem >= 3)      asm volatile("s_waitcnt vmcnt(8)" ::: "memory");
    else if (rem == 2) asm volatile("s_waitcnt vmcnt(4)" ::: "memory");
    else               asm volatile("s_waitcnt vmcnt(0)" ::: "memory");
    __builtin_amdgcn_s_barrier();
    cur = (cur + 1) & 3;
    nxt = (nxt + 1) & 3;
  }
#undef STAGE_A
#undef STAGE_B

  // C/D layout: col = lane&15, row = (lane>>4)*4 + r  [m89-verified]
  const int crow0 = m0 + wr * 128 + (lane >> 4) * 4;
  const int ccol0 = n0 + wc * 64 + (lane & 15);
  if (BF16OUT) {
    u16* C = (u16*)Cv + (long long)z * sCz;
#pragma unroll
    for (int m = 0; m < 8; ++m)
#pragma unroll
      for (int n = 0; n < 4; ++n)
#pragma unroll
        for (int r = 0; r < 4; ++r)
          C[(long long)(crow0 + m * 16 + r) * ldc + ccol0 + n * 16] = f2bf(acc[m][n][r] * scale);
  } else {
    float* C = (float*)Cv + (long long)z * sCz;
#pragma unroll
    for (int m = 0; m < 8; ++m)
#pragma unroll
      for (int n = 0; n < 4; ++n)
#pragma unroll
        for (int r = 0; r < 4; ++r)
          C[(long long)(crow0 + m * 16 + r) * ldc + ccol0 + n * 16] = acc[m][n][r] * scale;
  }
}

// (b, i, s) fp32  ->  (b, s, i) bf16 ; one 64x64 tile per block, block (64,4)
__global__ __launch_bounds__(256) void conv_transpose(const float* __restrict__ src, u16* __restrict__ dst)
{
  const int b = blockIdx.z;
  const float* s = src + (long long)b * 1024 * 2048;
  u16* d = dst + (long long)b * 2048 * 1024;
  const int s0 = blockIdx.x * 64, i0 = blockIdx.y * 64;
  const int tx = threadIdx.x, ty = threadIdx.y;
  __shared__ float tile[64][65];
#pragma unroll
  for (int r = 0; r < 16; ++r)
    tile[r * 4 + ty][tx] = s[(long long)(i0 + r * 4 + ty) * 2048 + s0 + tx];
  __syncthreads();
#pragma unroll
  for (int r = 0; r < 16; ++r)
    d[(long long)(s0 + r * 4 + ty) * 1024 + i0 + tx] = f2bf(tile[tx][r * 4 + ty]);
}

__global__ __launch_bounds__(256) void conv_weights(
    const float* __restrict__ a, const float* __restrict__ b, const float* __restrict__ c,
    u16* __restrict__ oa, u16* __restrict__ ob, u16* __restrict__ oc)
{
  const int which = blockIdx.y;
  const float* s = which == 0 ? a : which == 1 ? b : c;
  u16* d = which == 0 ? oa : which == 1 ? ob : oc;
  const int idx = (blockIdx.x * 256 + threadIdx.x) * 4;
  f32x4 v = *(const f32x4*)(s + idx);
  u16x4 o;
#pragma unroll
  for (int j = 0; j < 4; ++j) o[j] = f2bf(v[j]);
  *(u16x4*)(d + idx) = o;
}

// Row t of S'[t,s] (bf16 in): mask by index (s<=t), max, sum-exp, write P bf16.
// One row per block; 256 threads x 8 elems = 2048.
__global__ __launch_bounds__(256) void col_softmax(const u16* __restrict__ S, u16* __restrict__ P)
{
  const int t = blockIdx.x;
  const long long rowOff = ((long long)blockIdx.y * 2048 + t) * 2048;
  const u16* row = S + rowOff;
  u16* prow = P + rowOff;
  const int tid = threadIdx.x;
  const int i0 = tid * 8;

  u16x8 a = *(const u16x8*)(row + i0);
  float v[8];
#pragma unroll
  for (int j = 0; j < 8; ++j)
    v[j] = (i0 + j <= t) ? bf2f(a[j]) : -1e30f;  // unwritten/masked discarded by index

  float m = v[0];
#pragma unroll
  for (int j = 1; j < 8; ++j) m = fmaxf(m, v[j]);
#pragma unroll
  for (int off = 32; off; off >>= 1) m = fmaxf(m, __shfl_xor(m, off));
  __shared__ float red[4];
  __shared__ float red2[4];
  if ((tid & 63) == 0) red[tid >> 6] = m;
  __syncthreads();
  m = fmaxf(fmaxf(red[0], red[1]), fmaxf(red[2], red[3]));

  float e[8]; float ssum = 0.f;
#pragma unroll
  for (int j = 0; j < 8; ++j) { e[j] = __expf(v[j] - m); ssum += e[j]; }
#pragma unroll
  for (int off = 32; off; off >>= 1) ssum += __shfl_xor(ssum, off);
  if ((tid & 63) == 0) red2[tid >> 6] = ssum;
  __syncthreads();
  ssum = red2[0] + red2[1] + red2[2] + red2[3];
  const float inv = 1.0f / ssum;
  u16x8 o;
#pragma unroll
  for (int j = 0; j < 8; ++j) o[j] = f2bf(e[j] * inv);
  *(u16x8*)(prow + i0) = o;
}

extern "C" void kernel_launch(void* const* d_in, const int* in_sizes, int n_in,
                              void* d_out, int out_size, void* d_ws, size_t ws_size,
                              hipStream_t stream)
{
  const float* Q  = (const float*)d_in[0];
  const float* K  = (const float*)d_in[1];
  const float* V  = (const float*)d_in[2];
  const float* WQ = (const float*)d_in[3];
  const float* WK = (const float*)d_in[4];
  const float* WV = (const float*)d_in[5];
  float* out = (float*)d_out;

  const size_t MB = 1ull << 20;
  char* w = (char*)d_ws;
  if (ws_size < 262 * MB) {
    fprintf(stderr, "kernel_launch: workspace too small (%zu B, need >= %zu B)\n",
            ws_size, (size_t)(262 * MB));
    return;
  }

  // ws layout (MB): [0,6) weights bf16 | [6,70) Qd_t | [70,134) Kd_t | [134,198) Vd
  // [198, ...) transient: transposed-input buffer (64MB), later S(bf16)+P(bf16) chunks
  u16* wq    = (u16*)(w + 0 * MB);
  u16* wk    = (u16*)(w + 2 * MB);
  u16* wv    = (u16*)(w + 4 * MB);
  u16* qdt   = (u16*)(w + 6 * MB);
  u16* kdt   = (u16*)(w + 70 * MB);
  u16* vd    = (u16*)(w + 134 * MB);
  u16* trans = (u16*)(w + 198 * MB);
  u16* S     = (u16*)(w + 198 * MB);

  long long freeMB = (long long)(ws_size / MB) - 198;
  int chunk = (int)(freeMB / 16);  // 8MB S + 8MB P per batch (both bf16)
  if (chunk > 8) chunk = 8;
  u16* P = (u16*)(w + (198 + (size_t)chunk * 8) * MB);

  conv_weights<<<dim3(1024, 3), 256, 0, stream>>>(WQ, WK, WV, wq, wk, wv);

  // Projections. Qd_t/Kd_t stored (b, seq, o) = one (32768 x 1024) GEMM each;
  // Vd stored (b, o, seq), per-batch z.
  conv_transpose<<<dim3(32, 16, 16), dim3(64, 4), 0, stream>>>(Q, trans);
  gemm_bt<true, true, false, false, false><<<dim3(4, 128, 1), 512, 0, stream>>>(
      trans, wq, qdt, 1024, 1024, 1024, 1024, 0, 0, 0, 1.0f);
  conv_transpose<<<dim3(32, 16, 16), dim3(64, 4), 0, stream>>>(K, trans);
  gemm_bt<true, true, false, false, false><<<dim3(4, 128, 1), 512, 0, stream>>>(
      trans, wk, kdt, 1024, 1024, 1024, 1024, 0, 0, 0, 1.0f);
  conv_transpose<<<dim3(32, 16, 16), dim3(64, 4), 0, stream>>>(V, trans);
  // Vd: default linear mapping: f0 mod 8 == s-block -> same B-panel per XCD.
  gemm_bt<true, false, false, false, false><<<dim3(8, 4, 16), 512, 0, stream>>>(
      wv, trans, vd, 1024, 1024, 1024, 2048,
      0, (long long)2048 * 1024, (long long)1024 * 2048, 1.0f);

  // Attention per batch-chunk:
  //  S'[t,s] = Kd_t[t,:]·Qd_t[s,:]/32 — compact triangular grid (36 live tiles/z)
  //  row-softmax over s (masked by index), S/P bf16
  //  out[o,t] = sum_s Vd[o,s] P[t,s] — KLIMIT, (o=4 x, t=8 y) grid: XCD gets
  //  one o-col x one t-parity -> 1.11x work skew only.
  for (int b0 = 0; b0 < 16; b0 += chunk) {
    const int nb = (16 - b0) < chunk ? (16 - b0) : chunk;
    gemm_bt<true, false, true, false, false><<<dim3(36, 1, nb), 512, 0, stream>>>(
        kdt + (long long)b0 * 2048 * 1024, qdt + (long long)b0 * 2048 * 1024, S,
        1024, 1024, 1024, 2048,
        (long long)2048 * 1024, (long long)2048 * 1024, (long long)2048 * 2048, 0.03125f);
    col_softmax<<<dim3(2048, nb), 256, 0, stream>>>(S, P);
    gemm_bt<false, false, false, true, true><<<dim3(4, 8, nb), 512, 0, stream>>>(
        vd + (long long)b0 * 1024 * 2048, P, out + (long long)b0 * 1024 * 2048,
        2048, 2048, 2048, 2048,
        (long long)1024 * 2048, (long long)2048 * 2048, (long long)1024 * 2048, 1.0f);
  }
}